// Round 7
// baseline (181.508 us; speedup 1.0000x reference)
//
#include <hip/hip_runtime.h>
#include <math.h>

#define NOBS 9
#define LATD 128

typedef float f2 __attribute__((ext_vector_type(2)));

__device__ __forceinline__ float silu_f(float x) { return x / (1.f + expf(-x)); }
__device__ __forceinline__ f2 splat2(float x) { return (f2){x, x}; }
__device__ __forceinline__ f2 fma2(f2 a, f2 b, f2 c) { return __builtin_elementwise_fma(a, b, c); }

// ---------------- lane-exchange primitives ----------------

template<int CTRL>
__device__ __forceinline__ float dpp_perm(float x) {
  return __int_as_float(__builtin_amdgcn_update_dpp(0, __float_as_int(x), CTRL, 0xF, 0xF, true));
}
template<int PAT>
__device__ __forceinline__ float ds_swz(float x) {
  return __int_as_float(__builtin_amdgcn_ds_swizzle(__float_as_int(x), PAT));
}
__device__ __forceinline__ float x4f(float x) { return ds_swz<0x101F>(x); }   // xor4

template<int CTRL>
__device__ __forceinline__ f2 dpp2f(f2 x) { return (f2){dpp_perm<CTRL>(x.x), dpp_perm<CTRL>(x.y)}; }
__device__ __forceinline__ f2 swz2_x4(f2 x) { return (f2){x4f(x.x), x4f(x.y)}; }
template<int M>
__device__ __forceinline__ f2 shfl2f(f2 x) { return (f2){__shfl_xor(x.x, M, 64), __shfl_xor(x.y, M, 64)}; }

__device__ __forceinline__ float wave_sum(float x) {
  x += dpp_perm<0xB1>(x);     // xor1
  x += dpp_perm<0x4E>(x);     // xor2
  x += x4f(x);                // xor4
  x += dpp_perm<0x128>(x);    // xor8
  x += ds_swz<0x401F>(x);     // xor16
  x += __shfl_xor(x, 32, 64); // xor32
  return x;
}

// ---------------- circuit gates: f2 u[4] = 8 amps/lane, 2 waves per row ----------------
// amp bits: [9]=wave w (q0), [8]=i bit1 (q1), [7]=i bit0 (q2), [6]=component j (q3),
// [5:0]=lane bits (q4..q9 -> 32,16,8,4,2,1)

__device__ __forceinline__ void rot2(f2& a, f2& b, float c, float s) {
  f2 na = fma2(splat2(-s), b, a * c);
  f2 nb = fma2(splat2(c),  b, a * s);
  a = na; b = nb;
}

__device__ __forceinline__ void apply_rys10(f2 u[4], int lane, int w,
                                            const float* __restrict__ cc,
                                            const float* __restrict__ ss,
                                            float* xbuf) {
  {  // q0: cross-wave butterfly through LDS (f2 = ds_write_b64)
    float c = cc[0], s = ss[0];
    float sp = w ? s : -s;
    f2* mine   = (f2*)(xbuf + w * 512);
    f2* theirs = (f2*)(xbuf + (1 - w) * 512);
#pragma unroll
    for (int i = 0; i < 4; ++i) mine[i * 64 + lane] = u[i];
    __syncthreads();
#pragma unroll
    for (int i = 0; i < 4; ++i) { f2 p = theirs[i * 64 + lane]; u[i] = fma2(splat2(c), u[i], p * sp); }
  }
  rot2(u[0], u[2], cc[1], ss[1]);  // q1
  rot2(u[1], u[3], cc[1], ss[1]);
  rot2(u[0], u[1], cc[2], ss[2]);  // q2
  rot2(u[2], u[3], cc[2], ss[2]);
  {  // q3: within-f2 rotation
    float c = cc[3], s = ss[3];
#pragma unroll
    for (int i = 0; i < 4; ++i) {
      float nx = fmaf(-s, u[i].y, c * u[i].x);
      float ny = fmaf( c, u[i].y, s * u[i].x);
      u[i] = (f2){nx, ny};
    }
  }
  { float c = cc[4], s = ss[4], sp = (lane & 32) ? s : -s;  // q4: xor32
#pragma unroll
    for (int i = 0; i < 4; ++i) { f2 p = shfl2f<32>(u[i]); u[i] = fma2(splat2(c), u[i], p * sp); } }
  { float c = cc[5], s = ss[5], sp = (lane & 16) ? s : -s;  // q5: xor16
#pragma unroll
    for (int i = 0; i < 4; ++i) { f2 p = shfl2f<16>(u[i]); u[i] = fma2(splat2(c), u[i], p * sp); } }
  { float c = cc[6], s = ss[6], sp = (lane & 8) ? s : -s;   // q6: xor8 (DPP)
#pragma unroll
    for (int i = 0; i < 4; ++i) { f2 p = dpp2f<0x128>(u[i]); u[i] = fma2(splat2(c), u[i], p * sp); } }
  { float c = cc[7], s = ss[7], sp = (lane & 4) ? s : -s;   // q7: xor4 (swizzle)
#pragma unroll
    for (int i = 0; i < 4; ++i) { f2 p = swz2_x4(u[i]); u[i] = fma2(splat2(c), u[i], p * sp); } }
  { float c = cc[8], s = ss[8], sp = (lane & 2) ? s : -s;   // q8: xor2 (DPP)
#pragma unroll
    for (int i = 0; i < 4; ++i) { f2 p = dpp2f<0x4E>(u[i]); u[i] = fma2(splat2(c), u[i], p * sp); } }
  { float c = cc[9], s = ss[9], sp = (lane & 1) ? s : -s;   // q9: xor1 (DPP)
#pragma unroll
    for (int i = 0; i < 4; ++i) { f2 p = dpp2f<0xB1>(u[i]); u[i] = fma2(splat2(c), u[i], p * sp); } }
}

__device__ __forceinline__ void cnot_ladder8(f2 u[4], int lane, int w) {
  {  // (q0,q1): ctrl = wave bit -> wave 1 flips i bit1
    bool cw = (w != 0);
    f2 t0 = u[0], t1 = u[1];
    u[0] = cw ? u[2] : u[0];  u[1] = cw ? u[3] : u[1];
    u[2] = cw ? t0   : u[2];  u[3] = cw ? t1   : u[3];
  }
  { f2 t = u[1]; u[1] = (f2){t.y, t.x}; t = u[3]; u[3] = (f2){t.y, t.x}; }  // (q2,q3)
  { bool c45 = (lane & 32);   // (q4,q5): xor16
#pragma unroll
    for (int i = 0; i < 4; ++i) { f2 p = shfl2f<16>(u[i]); u[i] = c45 ? p : u[i]; } }
  { bool c67 = (lane & 8);    // (q6,q7): xor4
#pragma unroll
    for (int i = 0; i < 4; ++i) { f2 p = swz2_x4(u[i]); u[i] = c67 ? p : u[i]; } }
  { bool c89 = (lane & 2);    // (q8,q9): xor1
#pragma unroll
    for (int i = 0; i < 4; ++i) { f2 p = dpp2f<0xB1>(u[i]); u[i] = c89 ? p : u[i]; } }
  { f2 t = u[2]; u[2] = u[3]; u[3] = t; }  // (q1,q2)
#pragma unroll
  for (int i = 0; i < 4; ++i) u[i].y = __shfl_xor(u[i].y, 32, 64);  // (q3,q4)
  { bool c56 = (lane & 16);   // (q5,q6): xor8
#pragma unroll
    for (int i = 0; i < 4; ++i) { f2 p = dpp2f<0x128>(u[i]); u[i] = c56 ? p : u[i]; } }
  { bool c78 = (lane & 4);    // (q7,q8): xor2
#pragma unroll
    for (int i = 0; i < 4; ++i) { f2 p = dpp2f<0x4E>(u[i]); u[i] = c78 ? p : u[i]; } }
}

// ---------------- fused kernel: 2 rows / 256 threads ----------------
// MODE 0: full (writes out). MODE 1: MLP only, obs:=cs (writes ws). MODE 2: circuit only (writes ws).

template<int MODE>
__global__ __launch_bounds__(256) void fused_kernel(
    const float* __restrict__ z, const float* __restrict__ t,
    const float* __restrict__ W1, const float* __restrict__ b1,
    const float* __restrict__ W2, const float* __restrict__ b2,
    const float* __restrict__ varp,
    const float* __restrict__ A_p, const float* __restrict__ D_p,
    const float* __restrict__ W3, const float* __restrict__ b3,
    const float* __restrict__ W4, const float* __restrict__ b4,
    float* __restrict__ out, float* __restrict__ wsf) {
  __shared__ f2    xs2[256];
  __shared__ float hs[2][256];
  __shared__ float xch[2][2][1024];
  __shared__ float cs[2][40], sn[2][40];
  __shared__ float vcs[60], vsn[60];
  __shared__ float part[2][2][NOBS];
  __shared__ float os[2][NOBS];

  int tid = threadIdx.x;
  int b0 = blockIdx.x * 2;

  if (tid < 60) {
    float s, c;
    sincosf(0.5f * varp[tid], &s, &c);
    vcs[tid] = c; vsn[tid] = s;
  }

  if constexpr (MODE != 2) {
    // ---- phase 1: x = [z, cos(t f), sin(t f)] (rows packed in f2) ----
    if (tid < 128) {
      xs2[tid] = (f2){z[b0 * 128 + tid], z[(b0 + 1) * 128 + tid]};
    } else {
      int i = tid - 128, j = i & 63;
      float freq = expf(-9.2103403719761836f * (float)j * (1.f / 64.f));
      float a0 = t[b0] * freq, a1 = t[b0 + 1] * freq;
      xs2[tid] = (i < 64) ? (f2){cosf(a0), cosf(a1)} : (f2){sinf(a0), sinf(a1)};
    }
    __syncthreads();

    // ---- phase 2: h = silu(x@W1 + b1), rows packed ----
    {
      f2 acc = splat2(b1[tid]);
#pragma unroll 4
      for (int k = 0; k < 256; k += 4) {
        float w0 = W1[(k + 0) * 256 + tid];
        float w1 = W1[(k + 1) * 256 + tid];
        float w2 = W1[(k + 2) * 256 + tid];
        float w3 = W1[(k + 3) * 256 + tid];
        acc = fma2(xs2[k + 0], splat2(w0), acc);
        acc = fma2(xs2[k + 1], splat2(w1), acc);
        acc = fma2(xs2[k + 2], splat2(w2), acc);
        acc = fma2(xs2[k + 3], splat2(w3), acc);
      }
      hs[0][tid] = silu_f(acc.x);
      hs[1][tid] = silu_f(acc.y);
    }
    __syncthreads();

    // ---- phase 3: ang = h@W2 + b2 -> cos/sin(ang/2) ----
    if (tid < 80) {
      int r = tid / 40, c = tid - r * 40;
      float acc = b2[c];
#pragma unroll 4
      for (int k = 0; k < 256; k += 4) {
        float4 h = *(const float4*)&hs[r][k];
        acc = fmaf(h.x, W2[(k + 0) * 40 + c], acc);
        acc = fmaf(h.y, W2[(k + 1) * 40 + c], acc);
        acc = fmaf(h.z, W2[(k + 2) * 40 + c], acc);
        acc = fmaf(h.w, W2[(k + 3) * 40 + c], acc);
      }
      float s, cv;
      sincosf(0.5f * acc, &s, &cv);
      cs[r][c] = cv; sn[r][c] = s;
    }
  } else {
    // MODE 2: synthetic angles from varp (no MLP dependency)
    if (tid < 80) {
      int r = tid / 40, c = tid - r * 40;
      float s, cv;
      sincosf(0.5f * varp[tid % 60], &s, &cv);
      cs[r][c] = cv; sn[r][c] = s;
    }
  }
  __syncthreads();

  // ---- phase 4: circuit (2 waves per row, 8 amps/lane) ----
  int W_id = tid >> 6;
  int row  = W_id >> 1;
  int w    = W_id & 1;
  int lane = tid & 63;

  if constexpr (MODE != 1) {
    const float* cc = cs[row];
    const float* ss = sn[row];
    float* xch_row = &xch[row][0][0];

    f2 u[4];
    {
      float base = w ? ss[0] : cc[0];
      base *= (lane & 32) ? ss[4] : cc[4];
      base *= (lane & 16) ? ss[5] : cc[5];
      base *= (lane & 8)  ? ss[6] : cc[6];
      base *= (lane & 4)  ? ss[7] : cc[7];
      base *= (lane & 2)  ? ss[8] : cc[8];
      base *= (lane & 1)  ? ss[9] : cc[9];
#pragma unroll
      for (int i = 0; i < 4; ++i) {
        float pp = base * ((i & 2) ? ss[1] : cc[1]) * ((i & 1) ? ss[2] : cc[2]);
        u[i] = (f2){pp * cc[3], pp * ss[3]};
      }
    }
    cnot_ladder8(u, lane, w);
    int idx = 0;
#pragma unroll 1
    for (int layer = 1; layer < 4; ++layer) {
      apply_rys10(u, lane, w, cc + layer * 10, ss + layer * 10, xch_row + (idx & 1) * 1024);
      ++idx;
      if (layer < 3) cnot_ladder8(u, lane, w);
    }
#pragma unroll 1
    for (int ly = 0; ly < 6; ++ly) {
      apply_rys10(u, lane, w, vcs + ly * 10, vsn + ly * 10, xch_row + (idx & 1) * 1024);
      ++idx;
      cnot_ladder8(u, lane, w);
    }

    {
      float* dmp = xch_row + 1024;
#pragma unroll
      for (int i = 0; i < 4; ++i) {
        dmp[w * 512 + (2 * i) * 64 + lane]     = u[i].x;
        dmp[w * 512 + (2 * i + 1) * 64 + lane] = u[i].y;
      }
    }
    __syncthreads();

    // expectation values
    {
      const float* dmp = xch[row][1];
      int wl = w * 64 + lane;
#pragma unroll 1
      for (int s = 0; s < NOBS; ++s) {
        const int r8 = 8 - s;
        const int stride = 1 << r8;
        float h10 = A_p[s*6+0], h20 = A_p[s*6+1], h21 = A_p[s*6+2];
        float h30 = A_p[s*6+3], h31 = A_p[s*6+4], h32 = A_p[s*6+5];
        float d0 = 2.f * D_p[s*4+1], d1 = 2.f * D_p[s*4+2], d2 = 2.f * D_p[s*4+3];
        float acc = 0.f;
#pragma unroll
        for (int k = 0; k < 2; ++k) {
          int p = wl + 128 * k;
          int a  = p >> r8;
          int rr = p & (stride - 1);
          int bse = (a << (r8 + 2)) + rr;
          float x0 = dmp[bse];
          float x1 = dmp[bse + stride];
          float x2 = dmp[bse + 2 * stride];
          float x3 = dmp[bse + 3 * stride];
          acc += d0 * x0 * x0 + d1 * x1 * x1 + d2 * x2 * x2
               + 2.f * (h10 * x1 * x0 + h20 * x2 * x0 + h21 * x2 * x1
                      + h30 * x3 * x0 + h31 * x3 * x1 + h32 * x3 * x2);
        }
        acc = wave_sum(acc);
        if (lane == 0) part[row][w][s] = acc;
      }
    }
    __syncthreads();
    if (tid < 2 * NOBS) {
      int r = tid / NOBS, s = tid - r * NOBS;
      float val = part[r][0][s] + part[r][1][s];
      os[r][s] = val;
      if constexpr (MODE == 2) wsf[(1 << 20) + blockIdx.x * 2 * NOBS + tid] = val;
    }
    __syncthreads();
  } else {
    // MODE 1: fake obs from enc cos values (keeps phases 1-3 live)
    if (tid < 2 * NOBS) {
      int r = tid / NOBS, s = tid - r * NOBS;
      os[r][s] = cs[r][s];
    }
    __syncthreads();
  }

  if constexpr (MODE != 2) {
    // ---- phase 5: out = silu(obs@W3+b3) @ W4 + b4 ----
    {
      f2 a = splat2(b3[tid]);
#pragma unroll
      for (int s = 0; s < NOBS; ++s) {
        float wv = W3[s * 256 + tid];
        a = fma2((f2){os[0][s], os[1][s]}, splat2(wv), a);
      }
      hs[0][tid] = silu_f(a.x);
      hs[1][tid] = silu_f(a.y);
    }
    __syncthreads();
    {
      int c = tid & 127, rg = tid >> 7;
      const float* h = hs[rg];
      float o = b4[c];
#pragma unroll 4
      for (int k = 0; k < 256; k += 4) {
        float w0 = W4[(k + 0) * 128 + c];
        float w1 = W4[(k + 1) * 128 + c];
        float w2 = W4[(k + 2) * 128 + c];
        float w3 = W4[(k + 3) * 128 + c];
        float4 ha = *(const float4*)&h[k];
        o = fmaf(ha.w, w3, fmaf(ha.z, w2, fmaf(ha.y, w1, fmaf(ha.x, w0, o))));
      }
      float* dst = (MODE == 0) ? out : wsf;
      dst[(b0 + rg) * LATD + c] = o;
    }
  }
}

// ---------------- launcher ----------------

extern "C" void kernel_launch(void* const* d_in, const int* in_sizes, int n_in,
                              void* d_out, int out_size, void* d_ws, size_t ws_size,
                              hipStream_t stream) {
  const float* z_t  = (const float*)d_in[0];
  const float* t    = (const float*)d_in[1];
  const float* W1   = (const float*)d_in[2];
  const float* b1   = (const float*)d_in[3];
  const float* W2   = (const float*)d_in[4];
  const float* b2   = (const float*)d_in[5];
  const float* varp = (const float*)d_in[6];
  const float* A_p  = (const float*)d_in[7];
  // d_in[8] = B_p: imaginary part of H -> contributes 0 for real psi
  const float* D_p  = (const float*)d_in[9];
  const float* W3   = (const float*)d_in[10];
  const float* b3   = (const float*)d_in[11];
  const float* W4   = (const float*)d_in[12];
  const float* b4   = (const float*)d_in[13];
  float* out = (float*)d_out;
  float* wsf = (float*)d_ws;

  int B = in_sizes[1];  // t has one element per batch row

  // MODE 0: real output. MODE 1/2: diagnostic ablation dispatches (write d_ws only).
  fused_kernel<0><<<B / 2, 256, 0, stream>>>(z_t, t, W1, b1, W2, b2, varp,
                                             A_p, D_p, W3, b3, W4, b4, out, wsf);
  fused_kernel<1><<<B / 2, 256, 0, stream>>>(z_t, t, W1, b1, W2, b2, varp,
                                             A_p, D_p, W3, b3, W4, b4, out, wsf);
  fused_kernel<2><<<B / 2, 256, 0, stream>>>(z_t, t, W1, b1, W2, b2, varp,
                                             A_p, D_p, W3, b3, W4, b4, out, wsf);
}

// Round 8
// 124.197 us; speedup vs baseline: 1.4614x; 1.4614x over previous
//
#include <hip/hip_runtime.h>
#include <math.h>

#define NOBS 9
#define LATD 128

typedef float f2 __attribute__((ext_vector_type(2)));

__device__ __forceinline__ float silu_f(float x) { return x / (1.f + expf(-x)); }
__device__ __forceinline__ f2 splat2(float x) { return (f2){x, x}; }
__device__ __forceinline__ f2 fma2(f2 a, f2 b, f2 c) { return __builtin_elementwise_fma(a, b, c); }

// ---------------- lane-exchange primitives ----------------

template<int CTRL>
__device__ __forceinline__ float dpp_perm(float x) {
  return __int_as_float(__builtin_amdgcn_update_dpp(0, __float_as_int(x), CTRL, 0xF, 0xF, true));
}
template<int PAT>
__device__ __forceinline__ float ds_swz(float x) {
  return __int_as_float(__builtin_amdgcn_ds_swizzle(__float_as_int(x), PAT));
}
__device__ __forceinline__ float x4f(float x) { return ds_swz<0x101F>(x); }   // xor4

__device__ __forceinline__ float wave_sum(float x) {
  x += dpp_perm<0xB1>(x);     // xor1
  x += dpp_perm<0x4E>(x);     // xor2
  x += x4f(x);                // xor4
  x += dpp_perm<0x128>(x);    // xor8
  x += ds_swz<0x401F>(x);     // xor16
  x += __shfl_xor(x, 32, 64); // xor32
  return x;
}

// ---------------- circuit gates (16 regs/lane, 1 wave per row) ----------------
// amp index bits: [9:6] = reg bits 3..0 (qubits 0..3), [5:0] = lane bits (qubits 4..9)

template<int M>
__device__ __forceinline__ void ry_reg(float v[16], float c, float s) {
#pragma unroll
  for (int r = 0; r < 16; ++r) {
    if ((r & M) == 0) {
      float p0 = v[r], p1 = v[r | M];
      v[r]     = c * p0 - s * p1;
      v[r | M] = s * p0 + c * p1;
    }
  }
}

__device__ __forceinline__ void apply_rys(float v[16], int lane,
                                          const float* __restrict__ cc,
                                          const float* __restrict__ ss) {
  ry_reg<8>(v, cc[0], ss[0]);
  ry_reg<4>(v, cc[1], ss[1]);
  ry_reg<2>(v, cc[2], ss[2]);
  ry_reg<1>(v, cc[3], ss[3]);
  { float c = cc[4], s = ss[4], sp = (lane & 32) ? s : -s;   // q4: xor32
#pragma unroll
    for (int r = 0; r < 16; ++r) { float p = __shfl_xor(v[r], 32, 64); v[r] = fmaf(c, v[r], sp * p); } }
  { float c = cc[5], s = ss[5], sp = (lane & 16) ? s : -s;   // q5: xor16
#pragma unroll
    for (int r = 0; r < 16; ++r) { float p = __shfl_xor(v[r], 16, 64); v[r] = fmaf(c, v[r], sp * p); } }
  { float c = cc[6], s = ss[6], sp = (lane & 8) ? s : -s;    // q6: xor8 (DPP ror8)
#pragma unroll
    for (int r = 0; r < 16; ++r) { float p = dpp_perm<0x128>(v[r]); v[r] = fmaf(c, v[r], sp * p); } }
  { float c = cc[7], s = ss[7], sp = (lane & 4) ? s : -s;    // q7: xor4 (swizzle)
#pragma unroll
    for (int r = 0; r < 16; ++r) { float p = x4f(v[r]); v[r] = fmaf(c, v[r], sp * p); } }
  { float c = cc[8], s = ss[8], sp = (lane & 2) ? s : -s;    // q8: xor2
#pragma unroll
    for (int r = 0; r < 16; ++r) { float p = dpp_perm<0x4E>(v[r]); v[r] = fmaf(c, v[r], sp * p); } }
  { float c = cc[9], s = ss[9], sp = (lane & 1) ? s : -s;    // q9: xor1
#pragma unroll
    for (int r = 0; r < 16; ++r) { float p = dpp_perm<0xB1>(v[r]); v[r] = fmaf(c, v[r], sp * p); } }
}

__device__ __forceinline__ void cnot_ladder(float v[16], int lane) {
  float t;
  // even phase: ctrl0: reg bit3 -> bit2 ; ctrl2: reg bit1 -> bit0
  t=v[8];  v[8]=v[12];  v[12]=t;
  t=v[9];  v[9]=v[13];  v[13]=t;
  t=v[10]; v[10]=v[14]; v[14]=t;
  t=v[11]; v[11]=v[15]; v[15]=t;
  t=v[2];  v[2]=v[3];   v[3]=t;
  t=v[6];  v[6]=v[7];   v[7]=t;
  t=v[10]; v[10]=v[11]; v[11]=t;
  t=v[14]; v[14]=v[15]; v[15]=t;
  // fused lane CNOTs (4,5),(6,7),(8,9): src = lane ^ ((lane&42)>>1)
  int se = lane ^ ((lane & 42) >> 1);
#pragma unroll
  for (int r = 0; r < 16; ++r) v[r] = __shfl(v[r], se, 64);
  // odd phase: ctrl1: reg bit2 -> bit1
  t=v[4];  v[4]=v[6];   v[6]=t;
  t=v[5];  v[5]=v[7];   v[7]=t;
  t=v[12]; v[12]=v[14]; v[14]=t;
  t=v[13]; v[13]=v[15]; v[15]=t;
  // fused (5,6),(7,8) lane perm + (3,4) mixed (reg bit0 ctrl -> lane xor32)
  int so  = lane ^ ((lane & 20) >> 1);
  int so1 = so ^ 32;
#pragma unroll
  for (int r = 0; r < 16; ++r) v[r] = __shfl(v[r], (r & 1) ? so1 : so, 64);
}

// ---------------- fused kernel: 4 rows / 256 threads ----------------

__global__ __launch_bounds__(256) void fused_kernel(
    const float* __restrict__ z, const float* __restrict__ t,
    const float* __restrict__ W1, const float* __restrict__ b1,
    const float* __restrict__ W2, const float* __restrict__ b2,
    const float* __restrict__ varp,
    const float* __restrict__ A_p, const float* __restrict__ D_p,
    const float* __restrict__ W3, const float* __restrict__ b3,
    const float* __restrict__ W4, const float* __restrict__ b4,
    float* __restrict__ out) {
  __shared__ f2    xsA[256], xsB[256];   // {row0,row1}, {row2,row3}
  __shared__ float hs[4][256];           // phase-2 output (row-major, float4-readable)
  __shared__ f2    hp[2][256];           // phase-5a output ({row0,row1},{row2,row3})
  __shared__ float dump[4][1024];
  __shared__ float cs[4][40], sn[4][40];
  __shared__ float vcs[60], vsn[60];
  __shared__ float os[4][NOBS];

  int tid = threadIdx.x;
  int b0 = blockIdx.x * 4;

  if (tid < 60) {
    float s, c;
    sincosf(0.5f * varp[tid], &s, &c);
    vcs[tid] = c; vsn[tid] = s;
  }

  // ---- phase 1: x = [z, cos(t f), sin(t f)] for 4 rows ----
  if (tid < 128) {
#pragma unroll
    for (int r = 0; r < 4; ++r) {
      float val = z[(b0 + r) * 128 + tid];
      if (r < 2) ((float*)xsA)[2 * tid + r]       = val;
      else       ((float*)xsB)[2 * tid + (r - 2)] = val;
    }
  } else {
    int i = tid - 128, j = i & 63;
    float freq = expf(-9.2103403719761836f * (float)j * (1.f / 64.f));
#pragma unroll
    for (int r = 0; r < 4; ++r) {
      float arg = t[b0 + r] * freq;
      float val = (i < 64) ? cosf(arg) : sinf(arg);
      int k = 128 + i;
      if (r < 2) ((float*)xsA)[2 * k + r]       = val;
      else       ((float*)xsB)[2 * k + (r - 2)] = val;
    }
  }
  __syncthreads();

  // ---- phase 2: h = silu(x@W1 + b1); 16-deep pipelined W1 loads ----
  {
    f2 a01 = splat2(b1[tid]), a23 = a01;
    float w[16];
#pragma unroll
    for (int j = 0; j < 16; ++j) w[j] = W1[j * 256 + tid];
#pragma unroll 1
    for (int k0 = 0; k0 < 256; k0 += 16) {
      int kn = (k0 + 16) & 255;          // wrap prefetch (last group reloads 0; harmless)
      float wn[16];
#pragma unroll
      for (int j = 0; j < 16; ++j) wn[j] = W1[(kn + j) * 256 + tid];
#pragma unroll
      for (int j = 0; j < 16; ++j) {
        a01 = fma2(xsA[k0 + j], splat2(w[j]), a01);
        a23 = fma2(xsB[k0 + j], splat2(w[j]), a23);
      }
#pragma unroll
      for (int j = 0; j < 16; ++j) w[j] = wn[j];
    }
    hs[0][tid] = silu_f(a01.x);
    hs[1][tid] = silu_f(a01.y);
    hs[2][tid] = silu_f(a23.x);
    hs[3][tid] = silu_f(a23.y);
  }
  __syncthreads();

  // ---- phase 3: ang = h@W2 + b2 -> cos/sin(ang/2); 160 outputs, pipelined ----
  if (tid < 160) {
    int r = tid / 40, c = tid - r * 40;
    float acc = b2[c];
    float w[16];
#pragma unroll
    for (int j = 0; j < 16; ++j) w[j] = W2[j * 40 + c];
#pragma unroll 1
    for (int k0 = 0; k0 < 256; k0 += 16) {
      int kn = (k0 + 16) & 255;
      float wn[16];
#pragma unroll
      for (int j = 0; j < 16; ++j) wn[j] = W2[(kn + j) * 40 + c];
#pragma unroll
      for (int j = 0; j < 16; ++j) acc = fmaf(hs[r][k0 + j], w[j], acc);
#pragma unroll
      for (int j = 0; j < 16; ++j) w[j] = wn[j];
    }
    float s, cv;
    sincosf(0.5f * acc, &s, &cv);
    cs[r][c] = cv; sn[r][c] = s;
  }
  __syncthreads();

  // ---- phase 4: circuit, wave = row, 16 amps/lane ----
  {
    int wave = tid >> 6;
    int lane = tid & 63;
    const float* cc = cs[wave];
    const float* ss = sn[wave];

    // layer 0 on |0..0>: product state
    float base = 1.f;
    base *= (lane & 32) ? ss[4] : cc[4];
    base *= (lane & 16) ? ss[5] : cc[5];
    base *= (lane & 8)  ? ss[6] : cc[6];
    base *= (lane & 4)  ? ss[7] : cc[7];
    base *= (lane & 2)  ? ss[8] : cc[8];
    base *= (lane & 1)  ? ss[9] : cc[9];
    float v[16];
#pragma unroll
    for (int r = 0; r < 16; ++r) {
      float p = base;
      p *= (r & 8) ? ss[0] : cc[0];
      p *= (r & 4) ? ss[1] : cc[1];
      p *= (r & 2) ? ss[2] : cc[2];
      p *= (r & 1) ? ss[3] : cc[3];
      v[r] = p;
    }
    cnot_ladder(v, lane);
#pragma unroll 1
    for (int layer = 1; layer < 4; ++layer) {
      apply_rys(v, lane, cc + layer * 10, ss + layer * 10);
      if (layer < 3) cnot_ladder(v, lane);
    }
#pragma unroll 1
    for (int ly = 0; ly < 6; ++ly) {
      apply_rys(v, lane, vcs + ly * 10, vsn + ly * 10);
      cnot_ladder(v, lane);
    }

    float* sw = dump[wave];
#pragma unroll
    for (int r = 0; r < 16; ++r) sw[r * 64 + lane] = v[r];

    // expectation values (obs s acts on amp bits (9-s, 8-s)); same-wave LDS read, no barrier
#pragma unroll 1
    for (int s = 0; s < NOBS; ++s) {
      const int r8 = 8 - s;
      const int stride = 1 << r8;
      float h10 = A_p[s*6+0], h20 = A_p[s*6+1], h21 = A_p[s*6+2];
      float h30 = A_p[s*6+3], h31 = A_p[s*6+4], h32 = A_p[s*6+5];
      float d0 = 2.f * D_p[s*4+1], d1 = 2.f * D_p[s*4+2], d2 = 2.f * D_p[s*4+3];
      float acc = 0.f;
#pragma unroll
      for (int k = 0; k < 4; ++k) {
        int p = lane + 64 * k;
        int a  = p >> r8;
        int rr = p & (stride - 1);
        int bse = (a << (r8 + 2)) + rr;
        float x0 = sw[bse];
        float x1 = sw[bse + stride];
        float x2 = sw[bse + 2 * stride];
        float x3 = sw[bse + 3 * stride];
        acc += d0 * x0 * x0 + d1 * x1 * x1 + d2 * x2 * x2
             + 2.f * (h10 * x1 * x0 + h20 * x2 * x0 + h21 * x2 * x1
                    + h30 * x3 * x0 + h31 * x3 * x1 + h32 * x3 * x2);
      }
      acc = wave_sum(acc);
      if (lane == 0) os[wave][s] = acc;
    }
  }
  __syncthreads();

  // ---- phase 5a: hh = silu(obs@W3 + b3) ----
  {
    f2 a01 = splat2(b3[tid]), a23 = a01;
#pragma unroll
    for (int s = 0; s < NOBS; ++s) {
      float wv = W3[s * 256 + tid];
      a01 = fma2((f2){os[0][s], os[1][s]}, splat2(wv), a01);
      a23 = fma2((f2){os[2][s], os[3][s]}, splat2(wv), a23);
    }
    hp[0][tid] = (f2){silu_f(a01.x), silu_f(a01.y)};
    hp[1][tid] = (f2){silu_f(a23.x), silu_f(a23.y)};
  }
  __syncthreads();

  // ---- phase 5b: out = hh@W4 + b4; 16-deep pipelined W4 loads ----
  {
    int c = tid & 127, rg = tid >> 7;    // rg=0 -> rows 0,1 ; rg=1 -> rows 2,3
    const f2* hr = hp[rg];
    f2 acc = splat2(b4[c]);
    float w[16];
#pragma unroll
    for (int j = 0; j < 16; ++j) w[j] = W4[j * 128 + c];
#pragma unroll 1
    for (int k0 = 0; k0 < 256; k0 += 16) {
      int kn = (k0 + 16) & 255;
      float wn[16];
#pragma unroll
      for (int j = 0; j < 16; ++j) wn[j] = W4[(kn + j) * 128 + c];
#pragma unroll
      for (int j = 0; j < 16; ++j) acc = fma2(hr[k0 + j], splat2(w[j]), acc);
#pragma unroll
      for (int j = 0; j < 16; ++j) w[j] = wn[j];
    }
    out[(b0 + rg * 2) * LATD + c]     = acc.x;
    out[(b0 + rg * 2 + 1) * LATD + c] = acc.y;
  }
}

// ---------------- launcher ----------------

extern "C" void kernel_launch(void* const* d_in, const int* in_sizes, int n_in,
                              void* d_out, int out_size, void* d_ws, size_t ws_size,
                              hipStream_t stream) {
  const float* z_t  = (const float*)d_in[0];
  const float* t    = (const float*)d_in[1];
  const float* W1   = (const float*)d_in[2];
  const float* b1   = (const float*)d_in[3];
  const float* W2   = (const float*)d_in[4];
  const float* b2   = (const float*)d_in[5];
  const float* varp = (const float*)d_in[6];
  const float* A_p  = (const float*)d_in[7];
  // d_in[8] = B_p: imaginary part of H -> contributes 0 for real psi
  const float* D_p  = (const float*)d_in[9];
  const float* W3   = (const float*)d_in[10];
  const float* b3   = (const float*)d_in[11];
  const float* W4   = (const float*)d_in[12];
  const float* b4   = (const float*)d_in[13];
  float* out = (float*)d_out;

  int B = in_sizes[1];  // t has one element per batch row

  fused_kernel<<<B / 4, 256, 0, stream>>>(z_t, t, W1, b1, W2, b2, varp,
                                          A_p, D_p, W3, b3, W4, b4, out);
}